// Round 2
// baseline (2912.516 us; speedup 1.0000x reference)
//
#include <hip/hip_runtime.h>
#include <hip/hip_bf16.h>

#define N_NODES 100000
#define E_EDGES 50000
#define NNZ_CNT 1600000
#define C_IN 128
#define H_OUT 256

// ---------------------------------------------------------------------------
// Kernel 1: write y and batch_0 (as f32) into d_out; zero the x1 accumulator
// in d_ws (must be re-zeroed every call: ws is poisoned once, never restored).
// ---------------------------------------------------------------------------
__global__ __launch_bounds__(256) void init_out_ws(
    const int* __restrict__ y, const int* __restrict__ batch0,
    float* __restrict__ out, float* __restrict__ x1,
    int n, int ews4) {
  int i = blockIdx.x * 256 + threadIdx.x;
  if (i < ews4) ((float4*)x1)[i] = make_float4(0.f, 0.f, 0.f, 0.f);
  if (i < n) {
    out[i]     = (float)y[i];
    out[n + i] = (float)batch0[i];
  }
}

// ---------------------------------------------------------------------------
// Kernel 2: scatter  x1[row] += x[col] * val   (32 threads per nnz, float4)
// ---------------------------------------------------------------------------
__global__ __launch_bounds__(256) void scatter_kernel(
    const float* __restrict__ x, const int* __restrict__ rows,
    const int* __restrict__ cols, const float* __restrict__ vals,
    float* __restrict__ x1) {
  int t = blockIdx.x * 256 + threadIdx.x;   // NNZ*32 = 51.2M < 2^31
  int nnz  = t >> 5;
  int lane = t & 31;
  if (nnz >= NNZ_CNT) return;
  int   r = rows[nnz];
  int   c = cols[nnz];
  float v = vals[nnz];
  float4 xv = ((const float4*)x)[(size_t)c * (C_IN / 4) + lane];
  float* dst = x1 + (size_t)r * C_IN + lane * 4;
  atomicAdd(dst + 0, xv.x * v);
  atomicAdd(dst + 1, xv.y * v);
  atomicAdd(dst + 2, xv.z * v);
  atomicAdd(dst + 3, xv.w * v);
}

// ---------------------------------------------------------------------------
// Kernel 3: out = relu(A @ W + b), A:[M,128] f32, W:[128,256] f32, out f32.
// 256 threads: thread t owns output column h=t; block owns ROWS rows.
// A tile staged in LDS (ROWS*128*4 = 16KB); W streamed from L2 (128KB total).
// ---------------------------------------------------------------------------
template <int ROWS>
__global__ __launch_bounds__(256) void gemm_bias_relu(
    const float* __restrict__ A, const float* __restrict__ W,
    const float* __restrict__ bias, float* __restrict__ out, int M) {
  __shared__ float a_lds[ROWS][C_IN];
  const int h  = threadIdx.x;
  const int r0 = blockIdx.x * ROWS;

  // stage A rows (float4, coalesced)
  for (int i = threadIdx.x; i < ROWS * (C_IN / 4); i += 256) {
    int r  = i / (C_IN / 4);
    int k4 = i % (C_IN / 4);
    float4 v = make_float4(0.f, 0.f, 0.f, 0.f);
    if (r0 + r < M) v = ((const float4*)A)[(size_t)(r0 + r) * (C_IN / 4) + k4];
    *(float4*)&a_lds[r][k4 * 4] = v;
  }
  __syncthreads();

  float acc[ROWS];
  float b = bias[h];
#pragma unroll
  for (int r = 0; r < ROWS; ++r) acc[r] = b;

  for (int k = 0; k < C_IN; k += 4) {
    float w0 = W[(k + 0) * H_OUT + h];
    float w1 = W[(k + 1) * H_OUT + h];
    float w2 = W[(k + 2) * H_OUT + h];
    float w3 = W[(k + 3) * H_OUT + h];
#pragma unroll
    for (int r = 0; r < ROWS; ++r) {
      float4 xv = *(const float4*)&a_lds[r][k];
      acc[r] = fmaf(xv.w, w3, fmaf(xv.z, w2, fmaf(xv.y, w1, fmaf(xv.x, w0, acc[r]))));
    }
  }

#pragma unroll
  for (int r = 0; r < ROWS; ++r) {
    int row = r0 + r;
    if (row < M) out[(size_t)row * H_OUT + h] = fmaxf(acc[r], 0.f);
  }
}

// ---------------------------------------------------------------------------
extern "C" void kernel_launch(void* const* d_in, const int* in_sizes, int n_in,
                              void* d_out, int out_size, void* d_ws, size_t ws_size,
                              hipStream_t stream) {
  const float* x        = (const float*)d_in[0];
  const int*   inc_rows = (const int*)d_in[1];
  const int*   inc_cols = (const int*)d_in[2];
  const float* inc_vals = (const float*)d_in[3];
  const int*   y        = (const int*)d_in[4];
  const int*   batch0   = (const int*)d_in[5];
  const float* W0       = (const float*)d_in[6];
  const float* b0       = (const float*)d_in[7];
  const float* W1       = (const float*)d_in[8];
  const float* b1       = (const float*)d_in[9];

  float* out = (float*)d_out;
  float* x1  = (float*)d_ws;  // E*C floats = 25.6 MB scratch accumulator

  const int ews4 = E_EDGES * C_IN / 4;  // 1.6M float4s
  init_out_ws<<<(ews4 + 255) / 256, 256, 0, stream>>>(y, batch0, out, x1,
                                                      N_NODES, ews4);

  const int scatter_threads = NNZ_CNT * 32;
  scatter_kernel<<<(scatter_threads + 255) / 256, 256, 0, stream>>>(
      x, inc_rows, inc_cols, inc_vals, x1);

  float* x0_out = out + 2 * N_NODES;
  float* x1_out = out + 2 * N_NODES + (size_t)N_NODES * H_OUT;

  gemm_bias_relu<32><<<(N_NODES + 31) / 32, 256, 0, stream>>>(x, W0, b0,
                                                              x0_out, N_NODES);
  gemm_bias_relu<32><<<(E_EDGES + 31) / 32, 256, 0, stream>>>(x1, W1, b1,
                                                              x1_out, E_EDGES);
}

// Round 3
// 694.425 us; speedup vs baseline: 4.1941x; 4.1941x over previous
//
#include <hip/hip_runtime.h>
#include <hip/hip_bf16.h>

#define N_NODES 100000
#define E_EDGES 50000
#define NNZ_CNT 1600000
#define C_IN 128
#define H_OUT 256
#define SCAN_T 1024
#define SEG ((E_EDGES + SCAN_T - 1) / SCAN_T)  // 49

// ---------------------------------------------------------------------------
// Kernel 1: y/batch_0 -> out (f32); zero the per-edge counts (re-zero every
// call: ws is poisoned once and never restored).
// ---------------------------------------------------------------------------
__global__ __launch_bounds__(256) void init_kernel(
    const int* __restrict__ y, const int* __restrict__ batch0,
    float* __restrict__ out, int* __restrict__ counts) {
  int i = blockIdx.x * 256 + threadIdx.x;
  if (i < E_EDGES) counts[i] = 0;
  if (i < N_NODES) {
    out[i]            = (float)y[i];
    out[N_NODES + i]  = (float)batch0[i];
  }
}

// ---------------------------------------------------------------------------
// Kernel 2: histogram of nnz per edge (int atomics, L2-fast)
// ---------------------------------------------------------------------------
__global__ __launch_bounds__(256) void hist_kernel(
    const int* __restrict__ rows, int* __restrict__ counts) {
  int i = blockIdx.x * 256 + threadIdx.x;
  if (i < NNZ_CNT) atomicAdd(&counts[rows[i]], 1);
}

// ---------------------------------------------------------------------------
// Kernel 3: exclusive scan of counts[E] -> offsets[E+1], scan_pos[E]
// Single block: per-thread segment sums, Hillis-Steele over 1024 partials.
// ---------------------------------------------------------------------------
__global__ __launch_bounds__(SCAN_T) void scan_kernel(
    const int* __restrict__ counts, int* __restrict__ offsets,
    int* __restrict__ scan_pos) {
  __shared__ int part[SCAN_T];
  int t  = threadIdx.x;
  int lo = t * SEG;
  int hi = min(lo + SEG, E_EDGES);
  int s = 0;
  for (int i = lo; i < hi; ++i) s += counts[i];
  part[t] = s;
  __syncthreads();
  for (int d = 1; d < SCAN_T; d <<= 1) {
    int v = (t >= d) ? part[t - d] : 0;
    __syncthreads();
    part[t] += v;
    __syncthreads();
  }
  int run = (t == 0) ? 0 : part[t - 1];  // exclusive prefix of this segment
  for (int i = lo; i < hi; ++i) {
    offsets[i]  = run;
    scan_pos[i] = run;
    run += counts[i];
  }
  if (t == SCAN_T - 1) offsets[E_EDGES] = run;  // == NNZ_CNT
}

// ---------------------------------------------------------------------------
// Kernel 4: fill permutation: perm[pos] = nnz index, grouped by edge
// ---------------------------------------------------------------------------
__global__ __launch_bounds__(256) void fill_kernel(
    const int* __restrict__ rows, int* __restrict__ scan_pos,
    int* __restrict__ perm) {
  int i = blockIdx.x * 256 + threadIdx.x;
  if (i < NNZ_CNT) {
    int pos = atomicAdd(&scan_pos[rows[i]], 1);
    perm[pos] = i;
  }
}

// ---------------------------------------------------------------------------
// Kernel 5: per-edge gather-reduce. Block = 128 threads = one edge; thread t
// owns channel t. (col,val) staged to LDS in chunks; x row read is one
// coalesced 512B load per nnz; each x1 element written exactly once.
// ---------------------------------------------------------------------------
__global__ __launch_bounds__(128) void edge_reduce(
    const float* __restrict__ x, const int* __restrict__ cols,
    const float* __restrict__ vals, const int* __restrict__ perm,
    const int* __restrict__ offsets, float* __restrict__ x1) {
  __shared__ int   lcol[128];
  __shared__ float lval[128];
  int e = blockIdx.x;
  int t = threadIdx.x;
  int start = offsets[e], end = offsets[e + 1];
  float acc = 0.f;
  for (int base = start; base < end; base += 128) {
    int m = min(128, end - base);
    if (t < m) {
      int nz  = perm[base + t];
      lcol[t] = cols[nz];
      lval[t] = vals[nz];
    }
    __syncthreads();
    for (int j = 0; j < m; ++j)
      acc = fmaf(x[(size_t)lcol[j] * C_IN + t], lval[j], acc);
    __syncthreads();
  }
  x1[(size_t)e * C_IN + t] = acc;
}

// ---------------------------------------------------------------------------
// Kernel 6: out = relu(A @ W + b), A:[M,128] f32, W:[128,256] f32, out f32.
// 256 threads: thread t owns column h=t; block owns ROWS rows; A in LDS.
// ---------------------------------------------------------------------------
template <int ROWS>
__global__ __launch_bounds__(256) void gemm_bias_relu(
    const float* __restrict__ A, const float* __restrict__ W,
    const float* __restrict__ bias, float* __restrict__ out, int M) {
  __shared__ float a_lds[ROWS][C_IN];
  const int h  = threadIdx.x;
  const int r0 = blockIdx.x * ROWS;

  for (int i = threadIdx.x; i < ROWS * (C_IN / 4); i += 256) {
    int r  = i / (C_IN / 4);
    int k4 = i % (C_IN / 4);
    float4 v = make_float4(0.f, 0.f, 0.f, 0.f);
    if (r0 + r < M) v = ((const float4*)A)[(size_t)(r0 + r) * (C_IN / 4) + k4];
    *(float4*)&a_lds[r][k4 * 4] = v;
  }
  __syncthreads();

  float acc[ROWS];
  float b = bias[h];
#pragma unroll
  for (int r = 0; r < ROWS; ++r) acc[r] = b;

  for (int k = 0; k < C_IN; k += 4) {
    float w0 = W[(k + 0) * H_OUT + h];
    float w1 = W[(k + 1) * H_OUT + h];
    float w2 = W[(k + 2) * H_OUT + h];
    float w3 = W[(k + 3) * H_OUT + h];
#pragma unroll
    for (int r = 0; r < ROWS; ++r) {
      float4 xv = *(const float4*)&a_lds[r][k];
      acc[r] = fmaf(xv.w, w3, fmaf(xv.z, w2, fmaf(xv.y, w1, fmaf(xv.x, w0, acc[r]))));
    }
  }

#pragma unroll
  for (int r = 0; r < ROWS; ++r) {
    int row = r0 + r;
    if (row < M) out[(size_t)row * H_OUT + h] = fmaxf(acc[r], 0.f);
  }
}

// ---------------------------------------------------------------------------
extern "C" void kernel_launch(void* const* d_in, const int* in_sizes, int n_in,
                              void* d_out, int out_size, void* d_ws, size_t ws_size,
                              hipStream_t stream) {
  const float* x        = (const float*)d_in[0];
  const int*   inc_rows = (const int*)d_in[1];
  const int*   inc_cols = (const int*)d_in[2];
  const float* inc_vals = (const float*)d_in[3];
  const int*   y        = (const int*)d_in[4];
  const int*   batch0   = (const int*)d_in[5];
  const float* W0       = (const float*)d_in[6];
  const float* b0       = (const float*)d_in[7];
  const float* W1       = (const float*)d_in[8];
  const float* b1       = (const float*)d_in[9];

  float* out = (float*)d_out;

  // ws layout (bytes): x1[E*C f32]=25.6MB | counts[E] | offsets[E+1] |
  //                    scan_pos[E] | perm[NNZ] = ~32.3MB total
  char* ws = (char*)d_ws;
  float* x1      = (float*)ws;                     ws += (size_t)E_EDGES * C_IN * 4;
  int*   counts  = (int*)ws;                       ws += (size_t)E_EDGES * 4;
  int*   offsets = (int*)ws;                       ws += (size_t)(E_EDGES + 1) * 4;
  int*   scanpos = (int*)ws;                       ws += (size_t)E_EDGES * 4;
  int*   perm    = (int*)ws;

  init_kernel<<<(N_NODES + 255) / 256, 256, 0, stream>>>(y, batch0, out, counts);
  hist_kernel<<<(NNZ_CNT + 255) / 256, 256, 0, stream>>>(inc_rows, counts);
  scan_kernel<<<1, SCAN_T, 0, stream>>>(counts, offsets, scanpos);
  fill_kernel<<<(NNZ_CNT + 255) / 256, 256, 0, stream>>>(inc_rows, scanpos, perm);
  edge_reduce<<<E_EDGES, 128, 0, stream>>>(x, inc_cols, inc_vals, perm, offsets, x1);

  float* x0_out = out + 2 * N_NODES;
  float* x1_out = out + 2 * N_NODES + (size_t)N_NODES * H_OUT;

  gemm_bias_relu<32><<<(N_NODES + 31) / 32, 256, 0, stream>>>(x, W0, b0,
                                                              x0_out, N_NODES);
  gemm_bias_relu<32><<<(E_EDGES + 31) / 32, 256, 0, stream>>>(x1, W1, b1,
                                                              x1_out, E_EDGES);
}

// Round 4
// 416.823 us; speedup vs baseline: 6.9874x; 1.6660x over previous
//
#include <hip/hip_runtime.h>

#define N_NODES 100000
#define E_EDGES 50000
#define NNZ_CNT 1600000
#define C_IN 128
#define H_OUT 256
#define SCAN_T 1024
#define SEG ((E_EDGES + SCAN_T - 1) / SCAN_T)  // 49

typedef __attribute__((ext_vector_type(8))) short short8;   // 8 bf16 = 4 VGPR
typedef __attribute__((ext_vector_type(4))) float f32x4;    // MFMA accumulator

// RNE float->bf16 (bit-exact enough vs HW cvt; inputs are finite)
__device__ __forceinline__ ushort f2b(float f) {
  union { float f; uint u; } v; v.f = f;
  return (ushort)((v.u + 0x7FFFu + ((v.u >> 16) & 1u)) >> 16);
}
__device__ __forceinline__ float b2f(ushort u) {
  union { uint u; float f; } v; v.u = ((uint)u) << 16;
  return v.f;
}

// ---------------------------------------------------------------------------
// Kernel 1: y/batch_0 -> out (f32); zero counts; convert x (f32) -> xb (bf16).
// ---------------------------------------------------------------------------
__global__ __launch_bounds__(256) void init_kernel(
    const float* __restrict__ x, const int* __restrict__ y,
    const int* __restrict__ batch0, ushort* __restrict__ xb,
    float* __restrict__ out, int* __restrict__ counts, int nconv4) {
  int i = blockIdx.x * 256 + threadIdx.x;
  if (i < nconv4) {  // 4 floats -> 4 bf16 (8B store)
    float4 v = ((const float4*)x)[i];
    ushort4 u;
    u.x = f2b(v.x); u.y = f2b(v.y); u.z = f2b(v.z); u.w = f2b(v.w);
    ((ushort4*)xb)[i] = u;
  }
  if (i < E_EDGES) counts[i] = 0;
  if (i < N_NODES) {
    out[i]           = (float)y[i];
    out[N_NODES + i] = (float)batch0[i];
  }
}

// ---------------------------------------------------------------------------
// Kernel 2: histogram of nnz per edge
// ---------------------------------------------------------------------------
__global__ __launch_bounds__(256) void hist_kernel(
    const int* __restrict__ rows, int* __restrict__ counts) {
  int i = blockIdx.x * 256 + threadIdx.x;
  if (i < NNZ_CNT) atomicAdd(&counts[rows[i]], 1);
}

// ---------------------------------------------------------------------------
// Kernel 3: exclusive scan counts[E] -> offsets[E+1], scan_pos[E]
// ---------------------------------------------------------------------------
__global__ __launch_bounds__(SCAN_T) void scan_kernel(
    const int* __restrict__ counts, int* __restrict__ offsets,
    int* __restrict__ scan_pos) {
  __shared__ int part[SCAN_T];
  int t = threadIdx.x;
  int lo = t * SEG;
  int hi = min(lo + SEG, E_EDGES);
  int s = 0;
  for (int i = lo; i < hi; ++i) s += counts[i];
  part[t] = s;
  __syncthreads();
  for (int d = 1; d < SCAN_T; d <<= 1) {
    int v = (t >= d) ? part[t - d] : 0;
    __syncthreads();
    part[t] += v;
    __syncthreads();
  }
  int run = (t == 0) ? 0 : part[t - 1];
  for (int i = lo; i < hi; ++i) {
    offsets[i]  = run;
    scan_pos[i] = run;
    run += counts[i];
  }
  if (t == SCAN_T - 1) offsets[E_EDGES] = run;  // == NNZ_CNT
}

// ---------------------------------------------------------------------------
// Kernel 4: group (col,val) by edge: ecol/eval[pos] (scattered 4B writes,
// arrays L2-resident so write-back coalesces)
// ---------------------------------------------------------------------------
__global__ __launch_bounds__(256) void fill_kernel(
    const int* __restrict__ rows, const int* __restrict__ cols,
    const float* __restrict__ vals, int* __restrict__ scan_pos,
    int* __restrict__ ecol, float* __restrict__ eval) {
  int i = blockIdx.x * 256 + threadIdx.x;
  if (i < NNZ_CNT) {
    int pos = atomicAdd(&scan_pos[rows[i]], 1);
    ecol[pos] = cols[i];
    eval[pos] = vals[i];
  }
}

// ---------------------------------------------------------------------------
// Kernel 5: per-edge gather-reduce (bf16 x), writes x1 as bf16.
// Block = 128 threads = one edge; thread t owns channel t.
// ---------------------------------------------------------------------------
__global__ __launch_bounds__(128) void edge_reduce(
    const ushort* __restrict__ xb, const int* __restrict__ ecol,
    const float* __restrict__ eval, const int* __restrict__ offsets,
    ushort* __restrict__ x1b) {
  __shared__ int   lcol[128];
  __shared__ float lval[128];
  int e = blockIdx.x;
  int t = threadIdx.x;
  int start = offsets[e], end = offsets[e + 1];
  float acc = 0.f;
  for (int base = start; base < end; base += 128) {
    int m = min(128, end - base);
    if (t < m) { lcol[t] = ecol[base + t]; lval[t] = eval[base + t]; }
    __syncthreads();
    for (int j = 0; j < m; ++j)
      acc = fmaf(b2f(xb[(size_t)lcol[j] * C_IN + t]), lval[j], acc);
    __syncthreads();
  }
  x1b[(size_t)e * C_IN + t] = f2b(acc);
}

// ---------------------------------------------------------------------------
// Kernel 6: pack W (f32 [128,256]) into per-fragment bf16 layout:
// slot = (nt*4 + ks)*64 + lane holds 8 bf16: B[k = ks*32+(lane>>4)*8+j]
//                                            [c = nt*16 + (lane&15)]
// Both W0 and W1: 8192 slots total.
// ---------------------------------------------------------------------------
__global__ __launch_bounds__(256) void wprep_kernel(
    const float* __restrict__ W0, const float* __restrict__ W1,
    ushort* __restrict__ Wf) {
  int idx = blockIdx.x * 256 + threadIdx.x;  // 0..8191
  if (idx >= 8192) return;
  const float* W = (idx & 4096) ? W1 : W0;
  int slot = idx & 4095;
  int nt = slot >> 8, ks = (slot >> 6) & 3, lane = slot & 63;
  int c  = nt * 16 + (lane & 15);
  int kb = ks * 32 + ((lane >> 4) << 3);
  short8 v;
#pragma unroll
  for (int j = 0; j < 8; ++j) v[j] = (short)f2b(W[(kb + j) * H_OUT + c]);
  ((short8*)Wf)[idx] = v;
}

// ---------------------------------------------------------------------------
// Kernel 7: out = relu(A @ W + b) via MFMA. A:[M,128] bf16, Wf fragment-
// packed bf16, out f32. 256 threads = 4 waves in 2x2 grid over 64x256 tile.
// A/B frags share the same (lane,j)->k mapping so any intra-K HW permutation
// cancels. C/D: col=lane&15, row=(lane>>4)*4+reg (m89/m91-verified).
// ---------------------------------------------------------------------------
__global__ __launch_bounds__(256) void gemm_mfma(
    const ushort* __restrict__ A, const ushort* __restrict__ Wf,
    const float* __restrict__ bias, float* __restrict__ out, int M) {
  int wave = threadIdx.x >> 6;
  int lane = threadIdx.x & 63;
  int wm = wave >> 1, wn = wave & 1;          // 2x2 wave grid
  int r0 = blockIdx.x * 64 + wm * 32;

  int arow = lane & 15;
  int kgrp = lane >> 4;

  short8 a[2][4];
#pragma unroll
  for (int mt = 0; mt < 2; ++mt) {
    int row = min(r0 + mt * 16 + arow, M - 1);   // clamp; stores masked below
    const ushort* ap = A + (size_t)row * C_IN + kgrp * 8;
#pragma unroll
    for (int ks = 0; ks < 4; ++ks)
      a[mt][ks] = *(const short8*)(ap + ks * 32);
  }

  f32x4 acc[2][8];
#pragma unroll
  for (int mt = 0; mt < 2; ++mt)
#pragma unroll
    for (int nt = 0; nt < 8; ++nt) acc[mt][nt] = (f32x4){0.f, 0.f, 0.f, 0.f};

#pragma unroll
  for (int nt = 0; nt < 8; ++nt) {
    int gnt = wn * 8 + nt;
    const short8* bp = (const short8*)Wf + (size_t)(gnt * 4) * 64 + lane;
#pragma unroll
    for (int ks = 0; ks < 4; ++ks) {
      short8 b = bp[(size_t)ks * 64];
      acc[0][nt] = __builtin_amdgcn_mfma_f32_16x16x32_bf16(a[0][ks], b, acc[0][nt], 0, 0, 0);
      acc[1][nt] = __builtin_amdgcn_mfma_f32_16x16x32_bf16(a[1][ks], b, acc[1][nt], 0, 0, 0);
    }
  }

  int crow = kgrp * 4;
  int ccol = lane & 15;
#pragma unroll
  for (int mt = 0; mt < 2; ++mt) {
#pragma unroll
    for (int nt = 0; nt < 8; ++nt) {
      int col = wn * 128 + nt * 16 + ccol;
      float bb = bias[col];
#pragma unroll
      for (int reg = 0; reg < 4; ++reg) {
        int row = r0 + mt * 16 + crow + reg;
        if (row < M)
          out[(size_t)row * H_OUT + col] = fmaxf(acc[mt][nt][reg] + bb, 0.f);
      }
    }
  }
}

// ---------------------------------------------------------------------------
extern "C" void kernel_launch(void* const* d_in, const int* in_sizes, int n_in,
                              void* d_out, int out_size, void* d_ws, size_t ws_size,
                              hipStream_t stream) {
  const float* x        = (const float*)d_in[0];
  const int*   inc_rows = (const int*)d_in[1];
  const int*   inc_cols = (const int*)d_in[2];
  const float* inc_vals = (const float*)d_in[3];
  const int*   y        = (const int*)d_in[4];
  const int*   batch0   = (const int*)d_in[5];
  const float* W0       = (const float*)d_in[6];
  const float* b0       = (const float*)d_in[7];
  const float* W1       = (const float*)d_in[8];
  const float* b1       = (const float*)d_in[9];

  float* out = (float*)d_out;

  // ws layout: xb[N*128 bf16]=25.6MB | x1b[E*128 bf16]=12.8MB | ecol 6.4MB |
  // eval 6.4MB | counts | offsets | scanpos | Wf 128KB  (~52MB total)
  char* ws = (char*)d_ws;
  ushort* xb      = (ushort*)ws;  ws += (size_t)N_NODES * C_IN * 2;
  ushort* x1b     = (ushort*)ws;  ws += (size_t)E_EDGES * C_IN * 2;
  int*    ecol    = (int*)ws;     ws += (size_t)NNZ_CNT * 4;
  float*  eval    = (float*)ws;   ws += (size_t)NNZ_CNT * 4;
  int*    counts  = (int*)ws;     ws += (size_t)E_EDGES * 4;
  int*    offsets = (int*)ws;     ws += (size_t)(E_EDGES + 1) * 4;
  int*    scanpos = (int*)ws;     ws += (size_t)E_EDGES * 4;
  ushort* Wf      = (ushort*)ws;  // 8192*8 shorts = 128KB

  const int nconv4 = N_NODES * C_IN / 4;  // 3.2M
  init_kernel<<<(nconv4 + 255) / 256, 256, 0, stream>>>(x, y, batch0, xb, out,
                                                        counts, nconv4);
  hist_kernel<<<(NNZ_CNT + 255) / 256, 256, 0, stream>>>(inc_rows, counts);
  scan_kernel<<<1, SCAN_T, 0, stream>>>(counts, offsets, scanpos);
  fill_kernel<<<(NNZ_CNT + 255) / 256, 256, 0, stream>>>(
      inc_rows, inc_cols, inc_vals, scanpos, ecol, eval);
  wprep_kernel<<<32, 256, 0, stream>>>(W0, W1, Wf);
  edge_reduce<<<E_EDGES, 128, 0, stream>>>(xb, ecol, eval, offsets, x1b);

  float* x0_out = out + 2 * N_NODES;
  float* x1_out = out + 2 * N_NODES + (size_t)N_NODES * H_OUT;

  gemm_mfma<<<(N_NODES + 63) / 64, 256, 0, stream>>>(xb, Wf, b0, x0_out, N_NODES);
  gemm_mfma<<<(E_EDGES + 63) / 64, 256, 0, stream>>>(x1b, Wf + 8 * 4096, b1,
                                                     x1_out, E_EDGES);
}